// Round 14
// baseline (2353.630 us; speedup 1.0000x reference)
//
#include <hip/hip_runtime.h>
#include <math.h>

// Problem constants
constexpr int Bb = 64;    // batch
constexpr int Pp = 400;   // passage len
constexpr int Qq = 50;    // question len
constexpr int Ee = 300;   // embed dim
constexpr int Hh = 256;   // hidden
constexpr int H3 = 768;   // 3*H
constexpr int Dd = 512;   // 2*H

#define NEGC (-10000000.0f)
#define LOGTINY (-103.278929903f)   // log(float32(1e-45)) = log(2^-149)

typedef _Float16 h2 __attribute__((ext_vector_type(2)));
typedef _Float16 f16x8 __attribute__((ext_vector_type(8)));
typedef float f32x4 __attribute__((ext_vector_type(4)));

__device__ __forceinline__ float allred(float v){
  #pragma unroll
  for (int off = 1; off < 64; off <<= 1) v += __shfl_xor(v, off);
  return v;
}
__device__ __forceinline__ float allmax(float v){
  #pragma unroll
  for (int off = 1; off < 64; off <<= 1) v = fmaxf(v, __shfl_xor(v, off));
  return v;
}
__device__ __forceinline__ float sigm(float x){ return 1.f / (1.f + expf(-x)); }
__device__ __forceinline__ float tanh_c(float x){
  x = fminf(fmaxf(x, -15.f), 15.f);
  float e = expf(2.f * x);
  return (e - 1.f) / (e + 1.f);
}

// ---------------------------------------------------------------------------
// prep_emb16: emb fp32 [V][300] -> fp16 [V][320] zero-padded
// ---------------------------------------------------------------------------
__global__ __launch_bounds__(256) void prep_emb16(const float* __restrict__ emb,
                                                  _Float16* __restrict__ emb16){
  size_t idx = (size_t)blockIdx.x * 256 + threadIdx.x;   // pair id
  if (idx >= (size_t)100000 * 160) return;
  int col2 = (int)(idx % 160);
  size_t row = idx / 160;
  int c = col2 * 2;
  float2 v = make_float2(0.f, 0.f);
  if (c < Ee) v = *(const float2*)(emb + row * Ee + c);
  h2 o = { (_Float16)v.x, (_Float16)v.y };
  *(h2*)(emb16 + row * 320 + c) = o;
}

// ---------------------------------------------------------------------------
// prep_wih16: Wih fp32 [g][d][768][300] -> fp16 [g][d][768][320] padded
// ---------------------------------------------------------------------------
__global__ __launch_bounds__(256) void prep_wih16(const float* __restrict__ pW,
                                                  const float* __restrict__ qW,
                                                  _Float16* __restrict__ wih16){
  int idx = blockIdx.x * 256 + threadIdx.x;   // pair id: 2*2*768*160
  if (idx >= 2 * 2 * 768 * 160) return;
  int col2 = idx % 160;
  int r = idx / 160;           // g*1536 + d*768 + h
  int g = r / 1536;
  int dh = r % 1536;
  int c = col2 * 2;
  const float* W = g ? qW : pW;
  float2 v = make_float2(0.f, 0.f);
  if (c < Ee) v = *(const float2*)(W + (size_t)dh * Ee + c);
  h2 o = { (_Float16)v.x, (_Float16)v.y };
  *(h2*)(wih16 + (size_t)r * 320 + c) = o;
}

// ---------------------------------------------------------------------------
// prep_wB: pack Whh into MFMA B-fragment order (fp16 f16x8 per uint4 slot).
// uint4 idx = (((gd*8 + w)*8 + kt)*6 + cp)*64 + lane
//   gd = kind*2 + d ; wave w in [0,8) ; K-tile kt in [0,8) ; cp = g*2 + cg
//   n  = g*256 + w*32 + cg*16 + (lane&15)  (output unit row of Whh)
//   k0 = kt*32 + (lane>>4)*8               (input h col)
// value = fp16{ W[d][n][k0 .. k0+8) }  -- exactly the xproj-verified B layout.
// ---------------------------------------------------------------------------
__global__ __launch_bounds__(256) void prep_wB(const float* __restrict__ pW,
                                               const float* __restrict__ qW,
                                               uint4* __restrict__ wB){
  int idx = blockIdx.x * 256 + threadIdx.x;   // uint4 id, total 98304
  if (idx >= 98304) return;
  int lane = idx & 63;
  int r = idx >> 6;
  int cp = r % 6; r /= 6;
  int kt = r % 8; r /= 8;
  int w  = r % 8; r /= 8;
  int gd = r;                     // 0..3
  int d = gd & 1, kind = gd >> 1;
  int g = cp >> 1, cg = cp & 1;
  int n  = g * 256 + w * 32 + cg * 16 + (lane & 15);
  int k0 = kt * 32 + (lane >> 4) * 8;
  const float* W = kind ? qW : pW;
  const float* src = W + ((size_t)d * H3 + n) * Hh + k0;
  f16x8 v = { (_Float16)src[0], (_Float16)src[1], (_Float16)src[2], (_Float16)src[3],
              (_Float16)src[4], (_Float16)src[5], (_Float16)src[6], (_Float16)src[7] };
  wB[idx] = __builtin_bit_cast(uint4, v);
}

// ---------------------------------------------------------------------------
// xproj via MFMA, all-fp16 inputs (r12, unchanged)
// ---------------------------------------------------------------------------
__global__ __launch_bounds__(512) void xproj_mfma(const int* __restrict__ tok,
                                                  const _Float16* __restrict__ emb16,
                                                  const _Float16* __restrict__ wih16,
                                                  const float* __restrict__ bih,
                                                  _Float16* __restrict__ xp, int T){
  __shared__ __align__(16) _Float16 Af[128][72];
  __shared__ __align__(16) _Float16 Bf[128][72];
  int tid = threadIdx.x;
  int m0 = blockIdx.y * 128;
  int nt = blockIdx.x;                 // 0..11
  int d = nt / 6, h0 = (nt % 6) * 128;
  int wid = tid >> 6, lane = tid & 63;
  int wr = wid >> 2, wc = wid & 3;

  int r0 = tid >> 3;                    // 0..63
  int r1 = (tid + 512) >> 3;            // 64..127
  int cc = (tid & 7) * 8;
  const _Float16* eA0 = emb16 + (size_t)tok[m0 + r0] * 320;
  const _Float16* eA1 = emb16 + (size_t)tok[m0 + r1] * 320;
  const _Float16* wB0 = wih16 + ((size_t)d * H3 + h0 + r0) * 320;
  const _Float16* wB1 = wih16 + ((size_t)d * H3 + h0 + r1) * 320;

  f32x4 acc[4][2] = {};

  for (int k0 = 0; k0 < 320; k0 += 64){
    *(f16x8*)&Af[r0][cc] = *(const f16x8*)(eA0 + k0 + cc);
    *(f16x8*)&Af[r1][cc] = *(const f16x8*)(eA1 + k0 + cc);
    *(f16x8*)&Bf[r0][cc] = *(const f16x8*)(wB0 + k0 + cc);
    *(f16x8*)&Bf[r1][cc] = *(const f16x8*)(wB1 + k0 + cc);
    __syncthreads();
    #pragma unroll
    for (int kc = 0; kc < 2; ++kc){
      int kb = kc * 32 + (lane >> 4) * 8;
      f16x8 af[4], bf[2];
      #pragma unroll
      for (int i = 0; i < 4; ++i) af[i] = *(const f16x8*)&Af[wr * 64 + i * 16 + (lane & 15)][kb];
      #pragma unroll
      for (int jn = 0; jn < 2; ++jn) bf[jn] = *(const f16x8*)&Bf[wc * 32 + jn * 16 + (lane & 15)][kb];
      #pragma unroll
      for (int i = 0; i < 4; ++i)
        #pragma unroll
        for (int jn = 0; jn < 2; ++jn)
          acc[i][jn] = __builtin_amdgcn_mfma_f32_16x16x32_f16(af[i], bf[jn], acc[i][jn], 0, 0, 0);
    }
    __syncthreads();
  }

  #pragma unroll
  for (int jn = 0; jn < 2; ++jn){
    int h = h0 + wc * 32 + jn * 16 + (lane & 15);
    float bv = bih[d * H3 + h];
    #pragma unroll
    for (int i = 0; i < 4; ++i){
      #pragma unroll
      for (int r = 0; r < 4; ++r){
        int m = m0 + wr * 64 + i * 16 + (lane >> 4) * 4 + r;
        int bI = m / T, tI = m - bI * T;
        xp[(((size_t)d * Bb + bI) * T + tI) * H3 + h] = (_Float16)(acc[i][jn][r] + bv);
      }
    }
  }
}

// ---------------------------------------------------------------------------
// MFMA GRU. 16 WGs x 512 threads: WG = (gd, batch-group of 16).
// Per step: H[16x256] @ Whh^T -> 16x768 pre-activations via 16x16x32 MFMA.
// Wave w owns output cols {g*256 + w*32 + cg*16 + (lane&15)} (3 gates x 32
// units) = 48 B-fragments = 192 VGPR/AGPR, loaded ONCE (full residency:
// MFMA kernels get ~228 regs/thread at 512 thr, m97 precedent).
// C/D layout (m89): col=lane&15, row=(lane>>4)*4+reg -> each thread holds
// (r,z,n) for 4 batches x 2 units -> gates fully thread-local, h_old in
// regs, 1 barrier/step. A-frags from LDS hbuf[16][264] (pad -> 2-way free).
// ---------------------------------------------------------------------------
__global__ __launch_bounds__(512)
void gru_kernel(const int* __restrict__ ptok,
                const int* __restrict__ qtok,
                const _Float16* __restrict__ xpp,
                const _Float16* __restrict__ xpq,
                const uint4* __restrict__ wB,
                const float* __restrict__ pbhh,
                const float* __restrict__ qbhh,
                float* __restrict__ Hp,
                float* __restrict__ Hq){
  int wgid = blockIdx.x;           // 0..15
  int gd = wgid >> 2, bg = wgid & 3;
  bool isp = gd < 2;
  int d = gd & 1;
  int T = isp ? Pp : Qq;
  const int* tok = isp ? ptok : qtok;
  const _Float16* xbase = (isp ? xpp : xpq) + (size_t)d * Bb * T * H3;
  const float* bhh = (isp ? pbhh : qbhh) + d * H3;
  float* Hbase = isp ? Hp : Hq;

  __shared__ _Float16 hbuf[2][16][264];   // 16.5 KB, padded rows (2-way banks)

  int t = threadIdx.x, wv = t >> 6, lane = t & 63;

  // B fragments: 48 x f16x8, loaded once (full weight residency)
  f16x8 B[8][6];
  const uint4* wb = wB + ((size_t)(gd * 8 + wv)) * 48 * 64;
  #pragma unroll
  for (int kt = 0; kt < 8; ++kt)
    #pragma unroll
    for (int cp = 0; cp < 6; ++cp)
      B[kt][cp] = __builtin_bit_cast(f16x8, wb[(kt * 6 + cp) * 64 + lane]);

  int j0 = wv * 32 + (lane & 15);       // cg=0 unit ; cg=1 unit = j0+16
  float bias[3][2];
  #pragma unroll
  for (int g = 0; g < 3; ++g){
    bias[g][0] = bhh[g * 256 + j0];
    bias[g][1] = bhh[g * 256 + j0 + 16];
  }

  float hold[2][4] = {};                // [cg][r]
  for (int i = t; i < 16 * 264; i += 512) ((_Float16*)hbuf[1])[i] = (_Float16)0.f;
  __syncthreads();

  for (int s = 0; s < T; ++s){
    int tt = d ? (T - 1 - s) : s;
    const _Float16* hp = &hbuf[(s + 1) & 1][lane & 15][(lane >> 4) * 8];

    f32x4 acc[6] = {};
    #pragma unroll
    for (int kt = 0; kt < 8; ++kt){
      f16x8 aF = *(const f16x8*)(hp + kt * 32);
      #pragma unroll
      for (int cp = 0; cp < 6; ++cp)
        acc[cp] = __builtin_amdgcn_mfma_f32_16x16x32_f16(aF, B[kt][cp], acc[cp], 0, 0, 0);
    }

    // gates: thread-local. rows r -> local batch bl=(lane>>4)*4+r.
    #pragma unroll
    for (int r = 0; r < 4; ++r){
      int bl = (lane >> 4) * 4 + r;
      int b = bg * 16 + bl;
      float m = (tok[b * T + tt] != 0) ? 1.f : 0.f;
      const _Float16* xr = xbase + ((size_t)b * T + tt) * H3;
      float* ho = Hbase + ((size_t)b * T + tt) * Dd + d * Hh;
      #pragma unroll
      for (int cg = 0; cg < 2; ++cg){
        int j = j0 + cg * 16;
        float pr = acc[0 * 2 + cg][r] + bias[0][cg];
        float pz = acc[1 * 2 + cg][r] + bias[1][cg];
        float pn = acc[2 * 2 + cg][r] + bias[2][cg];
        float x0 = (float)xr[j];
        float x1 = (float)xr[256 + j];
        float x2 = (float)xr[512 + j];
        float rg = sigm(x0 + pr);
        float zg = sigm(x1 + pz);
        float ng = tanh_c(x2 + rg * pn);
        float hv = (1.f - zg) * ng + zg * hold[cg][r];
        float hm = m * hv + (1.f - m) * hold[cg][r];
        hold[cg][r] = hm;
        hbuf[s & 1][bl][j] = (_Float16)hm;
        ho[j] = hm * m;
      }
    }
    __syncthreads();
  }
}

// ---------------------------------------------------------------------------
// Attention + logits (unchanged)
// ---------------------------------------------------------------------------
__global__ __launch_bounds__(512) void attn_kernel(const float* __restrict__ Hp,
                                                   const float* __restrict__ Hq,
                                                   const int* __restrict__ ptok,
                                                   const int* __restrict__ qtok,
                                                   const float* __restrict__ start_w,
                                                   const float* __restrict__ sbp,
                                                   const float* __restrict__ end_w,
                                                   const float* __restrict__ ebp,
                                                   float* __restrict__ out){
  extern __shared__ __align__(16) float lds[];
  float* hqs = lds;               // 50*512
  float* s2s = hqs + Qq * Dd;     // 64
  float* qms = s2s + 64;          // 64
  float* scw = qms + 64;          // 8*64
  float* aw  = scw + 512;         // 8*64

  int b = blockIdx.y, pc = blockIdx.x;
  int tid = threadIdx.x, wid = tid >> 6, lane = tid & 63;
  float sb = sbp[0], eb = ebp[0];

  float w1r[8], w2r[8], w3r[8], e1r[8], e2r[8], e3r[8];
  #pragma unroll
  for (int i = 0; i < 8; ++i){
    int c = lane * 8 + i;
    w1r[i] = start_w[c]; w2r[i] = start_w[Dd + c]; w3r[i] = start_w[2 * Dd + c];
    e1r[i] = end_w[c];   e2r[i] = end_w[Dd + c];   e3r[i] = end_w[2 * Dd + c];
  }
  for (int idx = tid; idx < Qq * Dd; idx += 512) hqs[idx] = Hq[(size_t)b * Qq * Dd + idx];
  __syncthreads();

  for (int q = wid; q < Qq; q += 8){
    float part = 0.f;
    const float* hq = hqs + q * Dd + lane * 8;
    #pragma unroll
    for (int i = 0; i < 8; ++i) part += hq[i] * w2r[i];
    part = allred(part);
    if (lane == 0){
      s2s[q] = part;
      qms[q] = (qtok[b * Qq + q] != 0) ? 1.f : 0.f;
    }
  }
  __syncthreads();

  for (int p = pc * 100 + wid; p < pc * 100 + 100; p += 8){
    const float* hprow = Hp + ((size_t)b * Pp + p) * Dd + lane * 8;
    float4 hv0 = *(const float4*)hprow;
    float4 hv1 = *(const float4*)(hprow + 4);
    float hpc[8] = {hv0.x, hv0.y, hv0.z, hv0.w, hv1.x, hv1.y, hv1.z, hv1.w};
    float hw3[8], he3[8];
    float s1 = 0.f, ed = 0.f;
    #pragma unroll
    for (int i = 0; i < 8; ++i){
      hw3[i] = hpc[i] * w3r[i];
      he3[i] = hpc[i] * e3r[i];
      s1 += hpc[i] * w1r[i];
      ed += hpc[i] * e1r[i];
    }
    #pragma unroll
    for (int off = 1; off < 64; off <<= 1){
      s1 += __shfl_xor(s1, off);
      ed += __shfl_xor(ed, off);
    }
    for (int q = 0; q < Qq; ++q){
      const float4* hq4 = (const float4*)(hqs + q * Dd + lane * 8);
      float4 a0 = hq4[0], a1 = hq4[1];
      float dot = hw3[0] * a0.x + hw3[1] * a0.y + hw3[2] * a0.z + hw3[3] * a0.w
                + hw3[4] * a1.x + hw3[5] * a1.y + hw3[6] * a1.z + hw3[7] * a1.w;
      dot = allred(dot);
      if (lane == 0) scw[wid * 64 + q] = (s1 + s2s[q] + dot + sb) * qms[q];
    }
    float v = (lane < Qq) ? scw[wid * 64 + lane] : -1e30f;
    float M = allmax(v);
    float ev = (lane < Qq) ? expf(v - M) : 0.f;
    float S = allred(ev);
    float am = (lane < Qq) ? (ev / S) * qms[lane] : 0.f;
    float Sm = allred(am);
    float af = am / (Sm + 1e-13f);
    if (lane < Qq) aw[wid * 64 + lane] = af;
    float wv[8] = {0.f, 0.f, 0.f, 0.f, 0.f, 0.f, 0.f, 0.f};
    for (int q = 0; q < Qq; ++q){
      float aq = aw[wid * 64 + q];
      const float4* hq4 = (const float4*)(hqs + q * Dd + lane * 8);
      float4 a0 = hq4[0], a1 = hq4[1];
      wv[0] += aq * a0.x; wv[1] += aq * a0.y; wv[2] += aq * a0.z; wv[3] += aq * a0.w;
      wv[4] += aq * a1.x; wv[5] += aq * a1.y; wv[6] += aq * a1.z; wv[7] += aq * a1.w;
    }
    float acc2 = 0.f, acc3 = 0.f, acc4 = 0.f, acc5 = 0.f;
    #pragma unroll
    for (int i = 0; i < 8; ++i){
      acc2 += wv[i] * w2r[i];
      acc3 += hw3[i] * wv[i];
      acc4 += wv[i] * e2r[i];
      acc5 += he3[i] * wv[i];
    }
    #pragma unroll
    for (int off = 1; off < 64; off <<= 1){
      acc2 += __shfl_xor(acc2, off);
      acc3 += __shfl_xor(acc3, off);
      acc4 += __shfl_xor(acc4, off);
      acc5 += __shfl_xor(acc5, off);
    }
    if (lane == 0){
      bool pm = (ptok[b * Pp + p] != 0);
      out[(size_t)b * Pp + p]                   = pm ? (s1 + acc2 + acc3 + sb) : NEGC;
      out[(size_t)Bb * Pp + (size_t)b * Pp + p] = pm ? (ed + acc4 + acc5 + eb) : NEGC;
    }
  }
}

// ---------------------------------------------------------------------------
// log_softmax over p (unchanged)
// ---------------------------------------------------------------------------
__global__ __launch_bounds__(512) void lsm_kernel(const int* __restrict__ ptok,
                                                  float* __restrict__ out){
  int b = blockIdx.x >> 1, sel = blockIdx.x & 1;
  const float* lg = out + (size_t)sel * Bb * Pp + (size_t)b * Pp;
  float* o = out + (size_t)(2 + sel) * Bb * Pp + (size_t)b * Pp;
  int tid = threadIdx.x;
  __shared__ float red1[8];
  __shared__ float red2[8];
  float x = -1e30f;
  if (tid < Pp) x = lg[tid] + ((ptok[b * Pp + tid] != 0) ? 0.f : LOGTINY);
  float m = allmax(x);
  if ((tid & 63) == 0) red1[tid >> 6] = m;
  __syncthreads();
  float M = red1[0];
  #pragma unroll
  for (int i = 1; i < 8; ++i) M = fmaxf(M, red1[i]);
  float e = (tid < Pp) ? expf(x - M) : 0.f;
  float s = allred(e);
  if ((tid & 63) == 0) red2[tid >> 6] = s;
  __syncthreads();
  float S = 0.f;
  #pragma unroll
  for (int i = 0; i < 8; ++i) S += red2[i];
  if (tid < Pp) o[tid] = (x - M) - logf(S);
}

// ---------------------------------------------------------------------------
extern "C" void kernel_launch(void* const* d_in, const int* in_sizes, int n_in,
                              void* d_out, int out_size, void* d_ws, size_t ws_size,
                              hipStream_t stream){
  const int*   passage  = (const int*)d_in[0];
  const int*   question = (const int*)d_in[1];
  const float* emb      = (const float*)d_in[2];
  const float* pW_ih    = (const float*)d_in[3];
  const float* pW_hh    = (const float*)d_in[4];
  const float* pb_ih    = (const float*)d_in[5];
  const float* pb_hh    = (const float*)d_in[6];
  const float* qW_ih    = (const float*)d_in[7];
  const float* qW_hh    = (const float*)d_in[8];
  const float* qb_ih    = (const float*)d_in[9];
  const float* qb_hh    = (const float*)d_in[10];
  const float* start_w  = (const float*)d_in[11];
  const float* start_b  = (const float*)d_in[12];
  const float* end_w    = (const float*)d_in[13];
  const float* end_b    = (const float*)d_in[14];
  float* out = (float*)d_out;

  // workspace layout (float-sized units)
  float*     ws    = (float*)d_ws;
  uint4*     wB    = (uint4*)ws;                       //  98304 uint4 = 393216 f
  _Float16*  emb16 = (_Float16*)(ws + 393216);         // 16,000,000 f
  _Float16*  wih16 = (_Float16*)(ws + 16393216);       //   491520 f
  _Float16*  xpp   = (_Float16*)(ws + 16884736);       // 19660800 f
  _Float16*  xpq   = (_Float16*)(ws + 36545536);       //  2457600 f
  float*     Hp    = ws + 39003136;                    // 13107200 f
  float*     Hq    = ws + 52110336;                    //  1638400 f
  // total 53,748,736 floats = 215 MB

  hipLaunchKernelGGL(prep_wB, dim3(384), dim3(256), 0, stream, pW_hh, qW_hh, wB);
  hipLaunchKernelGGL(prep_emb16, dim3(62500), dim3(256), 0, stream, emb, emb16);
  hipLaunchKernelGGL(prep_wih16, dim3(1920), dim3(256), 0, stream, pW_ih, qW_ih, wih16);
  hipLaunchKernelGGL(xproj_mfma, dim3(12, 200), dim3(512), 0, stream,
                     passage, emb16, wih16, pb_ih, xpp, Pp);
  hipLaunchKernelGGL(xproj_mfma, dim3(12, 25), dim3(512), 0, stream,
                     question, emb16, wih16 + (size_t)2 * H3 * 320, qb_ih, xpq, Qq);
  hipLaunchKernelGGL(gru_kernel, dim3(16), dim3(512), 0, stream,
                     passage, question, xpp, xpq, wB, pb_hh, qb_hh, Hp, Hq);
  size_t attn_lds = (size_t)(Qq * Dd + 64 + 64 + 512 + 512) * sizeof(float);
  hipLaunchKernelGGL(attn_kernel, dim3(4, 64), dim3(512), attn_lds, stream,
                     Hp, Hq, passage, question, start_w, start_b, end_w, end_b, out);
  hipLaunchKernelGGL(lsm_kernel, dim3(128), dim3(512), 0, stream, passage, out);
}

// Round 15
// 964.887 us; speedup vs baseline: 2.4393x; 2.4393x over previous
//
#include <hip/hip_runtime.h>
#include <math.h>

// Problem constants
constexpr int Bb = 64;    // batch
constexpr int Pp = 400;   // passage len
constexpr int Qq = 50;    // question len
constexpr int Ee = 300;   // embed dim
constexpr int Hh = 256;   // hidden
constexpr int H3 = 768;   // 3*H
constexpr int Dd = 512;   // 2*H

#define NEGC (-10000000.0f)
#define LOGTINY (-103.278929903f)   // log(float32(1e-45)) = log(2^-149)

typedef _Float16 h2 __attribute__((ext_vector_type(2)));
typedef _Float16 f16x8 __attribute__((ext_vector_type(8)));
typedef float f32x4 __attribute__((ext_vector_type(4)));

__device__ __forceinline__ float allred(float v){
  #pragma unroll
  for (int off = 1; off < 64; off <<= 1) v += __shfl_xor(v, off);
  return v;
}
__device__ __forceinline__ float allmax(float v){
  #pragma unroll
  for (int off = 1; off < 64; off <<= 1) v = fmaxf(v, __shfl_xor(v, off));
  return v;
}
__device__ __forceinline__ float sigm(float x){ return 1.f / (1.f + expf(-x)); }

__device__ __forceinline__ float dot2f(unsigned a, unsigned b, float c){
#if __has_builtin(__builtin_amdgcn_fdot2)
  return __builtin_amdgcn_fdot2(__builtin_bit_cast(h2, a), __builtin_bit_cast(h2, b), c, false);
#else
  float r = c;
  asm("v_dot2_f32_f16 %0, %1, %2, %0" : "+v"(r) : "v"(a), "v"(b));
  return r;
#endif
}

#define U4C(v,c) ((c)==0?(v).x:((c)==1?(v).y:((c)==2?(v).z:(v).w)))

// ---------------------------------------------------------------------------
// gather_a: per used (b,t) position, copy emb[tok] fp32 -> fp16 row [320]
// (zero-padded). Only 28,800 rows instead of the 100k-vocab conversion.
// ---------------------------------------------------------------------------
__global__ __launch_bounds__(256) void gather_a(const int* __restrict__ ptok,
                                                const int* __restrict__ qtok,
                                                const float* __restrict__ emb,
                                                _Float16* __restrict__ Agp,
                                                _Float16* __restrict__ Agq){
  int idx = blockIdx.x * 256 + threadIdx.x;   // chunk id
  if (idx >= (25600 + 3200) * 40) return;
  int ck = idx % 40;
  int row = idx / 40;
  int tokv; _Float16* dst;
  if (row < 25600){ tokv = ptok[row]; dst = Agp + (size_t)row * 320; }
  else { int r = row - 25600; tokv = qtok[r]; dst = Agq + (size_t)r * 320; }
  int c = ck * 8;
  const float* src = emb + (size_t)tokv * Ee;
  f16x8 v;
  #pragma unroll
  for (int i = 0; i < 8; ++i) v[i] = (c + i < Ee) ? (_Float16)src[c + i] : (_Float16)0.f;
  *(f16x8*)(dst + c) = v;
}

// ---------------------------------------------------------------------------
// prep_wih16: Wih fp32 [g][d][768][300] -> fp16 [g][d][768][320] padded
// ---------------------------------------------------------------------------
__global__ __launch_bounds__(256) void prep_wih16(const float* __restrict__ pW,
                                                  const float* __restrict__ qW,
                                                  _Float16* __restrict__ wih16){
  int idx = blockIdx.x * 256 + threadIdx.x;   // pair id: 2*2*768*160
  if (idx >= 2 * 2 * 768 * 160) return;
  int col2 = idx % 160;
  int r = idx / 160;           // g*1536 + d*768 + h
  int g = r / 1536;
  int dh = r % 1536;
  int c = col2 * 2;
  const float* W = g ? qW : pW;
  float2 v = make_float2(0.f, 0.f);
  if (c < Ee) v = *(const float2*)(W + (size_t)dh * Ee + c);
  h2 o = { (_Float16)v.x, (_Float16)v.y };
  *(h2*)(wih16 + (size_t)r * 320 + c) = o;
}

// ---------------------------------------------------------------------------
// Pack Whh to fp16 pairs, 3-tier layout, split R5/L6/S5 quads per gate:
//   R (q 0..4):  block (gg*5 + q),            base 0      (60 blocks)
//   L (q 5..10): block (gg*6 + (q-5)),        base 30720  (72 blocks)
//   S (q 11..15):block (gg*5 + (q-11)),       base 67584  (60 blocks)
// (blocks are 512 uint4; gg = gd*3 + gate.) Thread t = half*256 + j owns
// pair p = half*64 + q*4 + c of row gate*256 + j.
// ---------------------------------------------------------------------------
__global__ __launch_bounds__(256) void prep_w16(const float* __restrict__ pW,
                                                const float* __restrict__ qW,
                                                unsigned* __restrict__ w16){
  int idx = blockIdx.x * 256 + threadIdx.x;   // u32 slot id (393216 total)
  if (idx >= 2 * 2 * 3 * 16 * 512 * 4) return;
  int c = idx & 3;
  int t = (idx >> 2) & 511;
  int q = (idx >> 11) & 15;
  int gg = idx >> 15;            // gd*3 + gate
  int gate = gg % 3, gd = gg / 3;
  int d = gd & 1, g = gd >> 1;
  int j = t & 255, half = t >> 8;
  int p = half * 64 + q * 4 + c;
  int row = gate * 256 + j;
  const float* W = g ? qW : pW;
  const float* src = W + ((size_t)d * H3 + row) * Hh + 2 * p;
  _Float16 a = (_Float16)src[0], b = (_Float16)src[1];
  unsigned short ua, ub;
  __builtin_memcpy(&ua, &a, 2); __builtin_memcpy(&ub, &b, 2);
  unsigned val = (unsigned)ua | ((unsigned)ub << 16);

  size_t u4idx;
  if (q < 5)       u4idx = ((size_t)gg * 5 + q) * 512 + t;
  else if (q < 11) u4idx = 30720 + ((size_t)gg * 6 + (q - 5)) * 512 + t;
  else             u4idx = 67584 + ((size_t)gg * 5 + (q - 11)) * 512 + t;
  w16[u4idx * 4 + c] = val;
}

// ---------------------------------------------------------------------------
// xproj via MFMA, all-fp16 inputs, gathered A rows (no token indirection).
// ---------------------------------------------------------------------------
__global__ __launch_bounds__(512) void xproj_mfma(const _Float16* __restrict__ Ag,
                                                  const _Float16* __restrict__ wih16,
                                                  const float* __restrict__ bih,
                                                  _Float16* __restrict__ xp, int T){
  __shared__ __align__(16) _Float16 Af[128][72];
  __shared__ __align__(16) _Float16 Bf[128][72];
  int tid = threadIdx.x;
  int m0 = blockIdx.y * 128;
  int nt = blockIdx.x;                 // 0..11
  int d = nt / 6, h0 = (nt % 6) * 128;
  int wid = tid >> 6, lane = tid & 63;
  int wr = wid >> 2, wc = wid & 3;

  int r0 = tid >> 3;                    // 0..63
  int r1 = (tid + 512) >> 3;            // 64..127
  int cc = (tid & 7) * 8;
  const _Float16* eA0 = Ag + (size_t)(m0 + r0) * 320;
  const _Float16* eA1 = Ag + (size_t)(m0 + r1) * 320;
  const _Float16* wB0 = wih16 + ((size_t)d * H3 + h0 + r0) * 320;
  const _Float16* wB1 = wih16 + ((size_t)d * H3 + h0 + r1) * 320;

  f32x4 acc[4][2] = {};

  for (int k0 = 0; k0 < 320; k0 += 64){
    *(f16x8*)&Af[r0][cc] = *(const f16x8*)(eA0 + k0 + cc);
    *(f16x8*)&Af[r1][cc] = *(const f16x8*)(eA1 + k0 + cc);
    *(f16x8*)&Bf[r0][cc] = *(const f16x8*)(wB0 + k0 + cc);
    *(f16x8*)&Bf[r1][cc] = *(const f16x8*)(wB1 + k0 + cc);
    __syncthreads();
    #pragma unroll
    for (int kc = 0; kc < 2; ++kc){
      int kb = kc * 32 + (lane >> 4) * 8;
      f16x8 af[4], bf[2];
      #pragma unroll
      for (int i = 0; i < 4; ++i) af[i] = *(const f16x8*)&Af[wr * 64 + i * 16 + (lane & 15)][kb];
      #pragma unroll
      for (int jn = 0; jn < 2; ++jn) bf[jn] = *(const f16x8*)&Bf[wc * 32 + jn * 16 + (lane & 15)][kb];
      #pragma unroll
      for (int i = 0; i < 4; ++i)
        #pragma unroll
        for (int jn = 0; jn < 2; ++jn)
          acc[i][jn] = __builtin_amdgcn_mfma_f32_16x16x32_f16(af[i], bf[jn], acc[i][jn], 0, 0, 0);
    }
    __syncthreads();
  }

  #pragma unroll
  for (int jn = 0; jn < 2; ++jn){
    int h = h0 + wc * 32 + jn * 16 + (lane & 15);
    float bv = bih[d * H3 + h];
    #pragma unroll
    for (int i = 0; i < 4; ++i){
      #pragma unroll
      for (int r = 0; r < 4; ++r){
        int m = m0 + wr * 64 + i * 16 + (lane >> 4) * 4 + r;
        int bI = m / T, tI = m - bI * T;
        xp[(((size_t)d * Bb + bI) * T + tI) * H3 + h] = (_Float16)(acc[i][jn][r] + bv);
      }
    }
  }
}

// ---------------------------------------------------------------------------
// 3-tier GRU (r12 structure), tiers rebalanced R60/L72/S60 into the
// measured 112-reg grant. Stream 123 KB/WG/step (L2-resident), consumed
// per-gate with 2 shared-readlane L-quads covering each issue group.
// ---------------------------------------------------------------------------
__global__ __launch_bounds__(512)
void gru_kernel(const int* __restrict__ ptok,
                const int* __restrict__ qtok,
                const _Float16* __restrict__ xpp,
                const _Float16* __restrict__ xpq,
                const unsigned* __restrict__ w16,
                const float* __restrict__ pbhh,
                const float* __restrict__ qbhh,
                float* __restrict__ Hp,
                float* __restrict__ Hq){
  int wg = blockIdx.x;
  bool isp = wg < 128;
  int lw = isp ? wg : wg - 128;
  int d = lw & 1, b = lw >> 1;
  int T = isp ? Pp : Qq;
  const int* tok = (isp ? ptok : qtok) + b * T;
  const _Float16* xrow = (isp ? xpp : xpq) + ((size_t)d * Bb + b) * T * H3;
  int gd = (isp ? 0 : 2) + d;
  const float* bhh = (isp ? pbhh : qbhh) + d * H3;
  float* Hout = (isp ? Hp : Hq) + (size_t)b * T * Dd + d * Hh;

  __shared__ __align__(16) uint4 ldsW[18 * 512];   // 147456 B, LDS weight tier
  __shared__ unsigned hbuf[2][128];                // packed fp16 h, double-buffered
  __shared__ float pa[Hh], pb[Hh], pn[Hh];

  int t = threadIdx.x;
  int j = t & 255, half = t >> 8, lane = t & 63;
  const uint4* u4w = (const uint4*)w16;

  // R tier: 5 quads per gate -> 60 u32
  unsigned wr0[20], wr1[20], wr2[20];
  #pragma unroll
  for (int q = 0; q < 5; ++q){
    uint4 v0 = u4w[((size_t)(gd * 3 + 0) * 5 + q) * 512 + t];
    uint4 v1 = u4w[((size_t)(gd * 3 + 1) * 5 + q) * 512 + t];
    uint4 v2 = u4w[((size_t)(gd * 3 + 2) * 5 + q) * 512 + t];
    wr0[4 * q + 0] = v0.x; wr0[4 * q + 1] = v0.y; wr0[4 * q + 2] = v0.z; wr0[4 * q + 3] = v0.w;
    wr1[4 * q + 0] = v1.x; wr1[4 * q + 1] = v1.y; wr1[4 * q + 2] = v1.z; wr1[4 * q + 3] = v1.w;
    wr2[4 * q + 0] = v2.x; wr2[4 * q + 1] = v2.y; wr2[4 * q + 2] = v2.z; wr2[4 * q + 3] = v2.w;
  }
  #pragma unroll
  for (int i = 0; i < 20; ++i){
    asm volatile("" : "+v"(wr0[i]));
    asm volatile("" : "+v"(wr1[i]));
    asm volatile("" : "+v"(wr2[i]));
  }

  // L tier -> LDS (18 blocks for this gd)
  #pragma unroll
  for (int u = 0; u < 18; ++u)
    ldsW[u * 512 + t] = u4w[30720 + ((size_t)gd * 18 + u) * 512 + t];
  const uint4* wS = u4w + 67584 + (size_t)(gd * 3) * 5 * 512;

  float bh0 = bhh[j], bh1 = bhh[Hh + j], bh2 = bhh[2 * Hh + j];
  float h_old = 0.f;
  if (t < 128) hbuf[1][t] = 0u;     // step 0 reads buf[1]
  __syncthreads();

  int t0 = d ? (T - 1) : 0;
  float pre0 = 0.f, pre1 = 0.f, pre2 = 0.f;
  if (half == 0){
    pre0 = (float)xrow[(size_t)t0 * H3 + j];
    pre1 = (float)xrow[(size_t)t0 * H3 + Hh + j];
    pre2 = (float)xrow[(size_t)t0 * H3 + 2 * Hh + j];
  }

  for (int s = 0; s < T; ++s){
    int tt = d ? (T - 1 - s) : s;
    unsigned vh = hbuf[(s + 1) & 1][half * 64 + lane];
    float a0 = 0.f, a1 = 0.f, a2 = 0.f;

    // shared-readlane L quad (all 3 gates), ql in [0,6)
    #define LPH(ql) { \
      uint4 l0 = ldsW[(0 * 6 + (ql)) * 512 + t]; \
      uint4 l1 = ldsW[(1 * 6 + (ql)) * 512 + t]; \
      uint4 l2 = ldsW[(2 * 6 + (ql)) * 512 + t]; \
      _Pragma("unroll") \
      for (int c = 0; c < 4; ++c){ \
        unsigned hv = (unsigned)__builtin_amdgcn_readlane((int)vh, 20 + (ql) * 4 + c); \
        a0 = dot2f(U4C(l0, c), hv, a0); \
        a1 = dot2f(U4C(l1, c), hv, a1); \
        a2 = dot2f(U4C(l2, c), hv, a2); } }
    // S consume: quad s of a gate (pairs 44..63)
    #define SCQ(ACC, si, A) { _Pragma("unroll") \
      for (int c = 0; c < 4; ++c){ \
        unsigned hv = (unsigned)__builtin_amdgcn_readlane((int)vh, 44 + (si) * 4 + c); \
        ACC = dot2f(U4C(A, c), hv, ACC); } }
    #define SISSG(g, A0, A1, A2, A3, A4) \
      uint4 A0 = wS[((g) * 5 + 0) * 512 + t]; \
      uint4 A1 = wS[((g) * 5 + 1) * 512 + t]; \
      uint4 A2 = wS[((g) * 5 + 2) * 512 + t]; \
      uint4 A3 = wS[((g) * 5 + 3) * 512 + t]; \
      uint4 A4 = wS[((g) * 5 + 4) * 512 + t];

    SISSG(0, s00, s01, s02, s03, s04)

    // R phase: pairs 0..19, shared readlane across gates
    #pragma unroll
    for (int q = 0; q < 5; ++q)
      #pragma unroll
      for (int c = 0; c < 4; ++c){
        unsigned hv = (unsigned)__builtin_amdgcn_readlane((int)vh, 4 * q + c);
        a0 = dot2f(wr0[q * 4 + c], hv, a0);
        a1 = dot2f(wr1[q * 4 + c], hv, a1);
        a2 = dot2f(wr2[q * 4 + c], hv, a2);
      }

    LPH(0) LPH(1)
    SCQ(a0, 0, s00) SCQ(a0, 1, s01) SCQ(a0, 2, s02) SCQ(a0, 3, s03) SCQ(a0, 4, s04)
    SISSG(1, s10, s11, s12, s13, s14)
    LPH(2) LPH(3)
    SCQ(a1, 0, s10) SCQ(a1, 1, s11) SCQ(a1, 2, s12) SCQ(a1, 3, s13) SCQ(a1, 4, s14)
    SISSG(2, s20, s21, s22, s23, s24)
    LPH(4) LPH(5)
    SCQ(a2, 0, s20) SCQ(a2, 1, s21) SCQ(a2, 2, s22) SCQ(a2, 3, s23) SCQ(a2, 4, s24)
    #undef LPH
    #undef SCQ
    #undef SISSG

    if (half == 1){ pa[j] = a0; pb[j] = a1; pn[j] = a2; }
    __syncthreads();
    if (half == 0){
      float xt0 = pre0, xt1 = pre1, xt2 = pre2;
      if (s + 1 < T){
        int tn = d ? (T - 2 - s) : (s + 1);
        pre0 = (float)xrow[(size_t)tn * H3 + j];
        pre1 = (float)xrow[(size_t)tn * H3 + Hh + j];
        pre2 = (float)xrow[(size_t)tn * H3 + 2 * Hh + j];
      }
      float g0 = a0 + pa[j] + bh0;
      float g1 = a1 + pb[j] + bh1;
      float g2 = a2 + pn[j] + bh2;
      float r = sigm(xt0 + g0);
      float z = sigm(xt1 + g1);
      float n = tanhf(xt2 + r * g2);
      float hnew = (1.f - z) * n + z * h_old;
      float m = (tok[tt] != 0) ? 1.f : 0.f;
      float hm = m * hnew + (1.f - m) * h_old;
      h_old = hm;
      ((_Float16*)hbuf[s & 1])[j] = (_Float16)hm;
      Hout[(size_t)tt * Dd + j] = hm * m;
    }
    __syncthreads();
  }
}

// ---------------------------------------------------------------------------
// Attention + logits (unchanged)
// ---------------------------------------------------------------------------
__global__ __launch_bounds__(512) void attn_kernel(const float* __restrict__ Hp,
                                                   const float* __restrict__ Hq,
                                                   const int* __restrict__ ptok,
                                                   const int* __restrict__ qtok,
                                                   const float* __restrict__ start_w,
                                                   const float* __restrict__ sbp,
                                                   const float* __restrict__ end_w,
                                                   const float* __restrict__ ebp,
                                                   float* __restrict__ out){
  extern __shared__ __align__(16) float lds[];
  float* hqs = lds;               // 50*512
  float* s2s = hqs + Qq * Dd;     // 64
  float* qms = s2s + 64;          // 64
  float* scw = qms + 64;          // 8*64
  float* aw  = scw + 512;         // 8*64

  int b = blockIdx.y, pc = blockIdx.x;
  int tid = threadIdx.x, wid = tid >> 6, lane = tid & 63;
  float sb = sbp[0], eb = ebp[0];

  float w1r[8], w2r[8], w3r[8], e1r[8], e2r[8], e3r[8];
  #pragma unroll
  for (int i = 0; i < 8; ++i){
    int c = lane * 8 + i;
    w1r[i] = start_w[c]; w2r[i] = start_w[Dd + c]; w3r[i] = start_w[2 * Dd + c];
    e1r[i] = end_w[c];   e2r[i] = end_w[Dd + c];   e3r[i] = end_w[2 * Dd + c];
  }
  for (int idx = tid; idx < Qq * Dd; idx += 512) hqs[idx] = Hq[(size_t)b * Qq * Dd + idx];
  __syncthreads();

  for (int q = wid; q < Qq; q += 8){
    float part = 0.f;
    const float* hq = hqs + q * Dd + lane * 8;
    #pragma unroll
    for (int i = 0; i < 8; ++i) part += hq[i] * w2r[i];
    part = allred(part);
    if (lane == 0){
      s2s[q] = part;
      qms[q] = (qtok[b * Qq + q] != 0) ? 1.f : 0.f;
    }
  }
  __syncthreads();

  for (int p = pc * 100 + wid; p < pc * 100 + 100; p += 8){
    const float* hprow = Hp + ((size_t)b * Pp + p) * Dd + lane * 8;
    float4 hv0 = *(const float4*)hprow;
    float4 hv1 = *(const float4*)(hprow + 4);
    float hpc[8] = {hv0.x, hv0.y, hv0.z, hv0.w, hv1.x, hv1.y, hv1.z, hv1.w};
    float hw3[8], he3[8];
    float s1 = 0.f, ed = 0.f;
    #pragma unroll
    for (int i = 0; i < 8; ++i){
      hw3[i] = hpc[i] * w3r[i];
      he3[i] = hpc[i] * e3r[i];
      s1 += hpc[i] * w1r[i];
      ed += hpc[i] * e1r[i];
    }
    #pragma unroll
    for (int off = 1; off < 64; off <<= 1){
      s1 += __shfl_xor(s1, off);
      ed += __shfl_xor(ed, off);
    }
    for (int q = 0; q < Qq; ++q){
      const float4* hq4 = (const float4*)(hqs + q * Dd + lane * 8);
      float4 a0 = hq4[0], a1 = hq4[1];
      float dot = hw3[0] * a0.x + hw3[1] * a0.y + hw3[2] * a0.z + hw3[3] * a0.w
                + hw3[4] * a1.x + hw3[5] * a1.y + hw3[6] * a1.z + hw3[7] * a1.w;
      dot = allred(dot);
      if (lane == 0) scw[wid * 64 + q] = (s1 + s2s[q] + dot + sb) * qms[q];
    }
    float v = (lane < Qq) ? scw[wid * 64 + lane] : -1e30f;
    float M = allmax(v);
    float ev = (lane < Qq) ? expf(v - M) : 0.f;
    float S = allred(ev);
    float am = (lane < Qq) ? (ev / S) * qms[lane] : 0.f;
    float Sm = allred(am);
    float af = am / (Sm + 1e-13f);
    if (lane < Qq) aw[wid * 64 + lane] = af;
    float wv[8] = {0.f, 0.f, 0.f, 0.f, 0.f, 0.f, 0.f, 0.f};
    for (int q = 0; q < Qq; ++q){
      float aq = aw[wid * 64 + q];
      const float4* hq4 = (const float4*)(hqs + q * Dd + lane * 8);
      float4 a0 = hq4[0], a1 = hq4[1];
      wv[0] += aq * a0.x; wv[1] += aq * a0.y; wv[2] += aq * a0.z; wv[3] += aq * a0.w;
      wv[4] += aq * a1.x; wv[5] += aq * a1.y; wv[6] += aq * a1.z; wv[7] += aq * a1.w;
    }
    float acc2 = 0.f, acc3 = 0.f, acc4 = 0.f, acc5 = 0.f;
    #pragma unroll
    for (int i = 0; i < 8; ++i){
      acc2 += wv[i] * w2r[i];
      acc3 += hw3[i] * wv[i];
      acc4 += wv[i] * e2r[i];
      acc5 += he3[i] * wv[i];
    }
    #pragma unroll
    for (int off = 1; off < 64; off <<= 1){
      acc2 += __shfl_xor(acc2, off);
      acc3 += __shfl_xor(acc3, off);
      acc4 += __shfl_xor(acc4, off);
      acc5 += __shfl_xor(acc5, off);
    }
    if (lane == 0){
      bool pm = (ptok[b * Pp + p] != 0);
      out[(size_t)b * Pp + p]                   = pm ? (s1 + acc2 + acc3 + sb) : NEGC;
      out[(size_t)Bb * Pp + (size_t)b * Pp + p] = pm ? (ed + acc4 + acc5 + eb) : NEGC;
    }
  }
}

// ---------------------------------------------------------------------------
// log_softmax over p (unchanged)
// ---------------------------------------------------------------------------
__global__ __launch_bounds__(512) void lsm_kernel(const int* __restrict__ ptok,
                                                  float* __restrict__ out){
  int b = blockIdx.x >> 1, sel = blockIdx.x & 1;
  const float* lg = out + (size_t)sel * Bb * Pp + (size_t)b * Pp;
  float* o = out + (size_t)(2 + sel) * Bb * Pp + (size_t)b * Pp;
  int tid = threadIdx.x;
  __shared__ float red1[8];
  __shared__ float red2[8];
  float x = -1e30f;
  if (tid < Pp) x = lg[tid] + ((ptok[b * Pp + tid] != 0) ? 0.f : LOGTINY);
  float m = allmax(x);
  if ((tid & 63) == 0) red1[tid >> 6] = m;
  __syncthreads();
  float M = red1[0];
  #pragma unroll
  for (int i = 1; i < 8; ++i) M = fmaxf(M, red1[i]);
  float e = (tid < Pp) ? expf(x - M) : 0.f;
  float s = allred(e);
  if ((tid & 63) == 0) red2[tid >> 6] = s;
  __syncthreads();
  float S = 0.f;
  #pragma unroll
  for (int i = 0; i < 8; ++i) S += red2[i];
  if (tid < Pp) o[tid] = (x - M) - logf(S);
}

// ---------------------------------------------------------------------------
extern "C" void kernel_launch(void* const* d_in, const int* in_sizes, int n_in,
                              void* d_out, int out_size, void* d_ws, size_t ws_size,
                              hipStream_t stream){
  const int*   passage  = (const int*)d_in[0];
  const int*   question = (const int*)d_in[1];
  const float* emb      = (const float*)d_in[2];
  const float* pW_ih    = (const float*)d_in[3];
  const float* pW_hh    = (const float*)d_in[4];
  const float* pb_ih    = (const float*)d_in[5];
  const float* pb_hh    = (const float*)d_in[6];
  const float* qW_ih    = (const float*)d_in[7];
  const float* qW_hh    = (const float*)d_in[8];
  const float* qb_ih    = (const float*)d_in[9];
  const float* qb_hh    = (const float*)d_in[10];
  const float* start_w  = (const float*)d_in[11];
  const float* start_b  = (const float*)d_in[12];
  const float* end_w    = (const float*)d_in[13];
  const float* end_b    = (const float*)d_in[14];
  float* out = (float*)d_out;

  // workspace layout (float-sized units)
  float*     ws    = (float*)d_ws;
  unsigned*  w16   = (unsigned*)ws;                    //   393216 u32
  _Float16*  wih16 = (_Float16*)(ws + 393216);         //   983040 halfs = 491520 f
  _Float16*  Agp   = (_Float16*)(ws + 884736);         //  8192000 halfs = 4096000 f
  _Float16*  Agq   = (_Float16*)(ws + 4980736);        //  1024000 halfs = 512000 f
  _Float16*  xpp   = (_Float16*)(ws + 5492736);        // 39321600 halfs = 19660800 f
  _Float16*  xpq   = (_Float16*)(ws + 25153536);       //  4915200 halfs = 2457600 f
  float*     Hp    = ws + 27611136;                    // 13107200 f
  float*     Hq    = ws + 40718336;                    //  1638400 f
  // total 42,356,736 floats = 169 MB

  hipLaunchKernelGGL(prep_w16, dim3(1536), dim3(256), 0, stream, pW_hh, qW_hh, w16);
  hipLaunchKernelGGL(gather_a, dim3(4500), dim3(256), 0, stream,
                     passage, question, emb, Agp, Agq);
  hipLaunchKernelGGL(prep_wih16, dim3(1920), dim3(256), 0, stream, pW_ih, qW_ih, wih16);
  hipLaunchKernelGGL(xproj_mfma, dim3(12, 200), dim3(512), 0, stream,
                     Agp, wih16, pb_ih, xpp, Pp);
  hipLaunchKernelGGL(xproj_mfma, dim3(12, 25), dim3(512), 0, stream,
                     Agq, wih16 + (size_t)2 * H3 * 320, qb_ih, xpq, Qq);
  hipLaunchKernelGGL(gru_kernel, dim3(256), dim3(512), 0, stream,
                     passage, question, xpp, xpq, w16, pb_hh, qb_hh, Hp, Hq);
  size_t attn_lds = (size_t)(Qq * Dd + 64 + 64 + 512 + 512) * sizeof(float);
  hipLaunchKernelGGL(attn_kernel, dim3(4, 64), dim3(512), attn_lds, stream,
                     Hp, Hq, passage, question, start_w, start_b, end_w, end_b, out);
  hipLaunchKernelGGL(lsm_kernel, dim3(128), dim3(512), 0, stream, passage, out);
}

// Round 16
// 938.884 us; speedup vs baseline: 2.5068x; 1.0277x over previous
//
#include <hip/hip_runtime.h>
#include <math.h>

// Problem constants
constexpr int Bb = 64;    // batch
constexpr int Pp = 400;   // passage len
constexpr int Qq = 50;    // question len
constexpr int Ee = 300;   // embed dim
constexpr int Hh = 256;   // hidden
constexpr int H3 = 768;   // 3*H
constexpr int Dd = 512;   // 2*H

#define NEGC (-10000000.0f)
#define LOGTINY (-103.278929903f)   // log(float32(1e-45)) = log(2^-149)

typedef _Float16 h2 __attribute__((ext_vector_type(2)));
typedef _Float16 f16x8 __attribute__((ext_vector_type(8)));
typedef float f32x4 __attribute__((ext_vector_type(4)));

__device__ __forceinline__ float allred(float v){
  #pragma unroll
  for (int off = 1; off < 64; off <<= 1) v += __shfl_xor(v, off);
  return v;
}
__device__ __forceinline__ float allmax(float v){
  #pragma unroll
  for (int off = 1; off < 64; off <<= 1) v = fmaxf(v, __shfl_xor(v, off));
  return v;
}
__device__ __forceinline__ float sigm(float x){ return 1.f / (1.f + expf(-x)); }

__device__ __forceinline__ float dot2f(unsigned a, unsigned b, float c){
#if __has_builtin(__builtin_amdgcn_fdot2)
  return __builtin_amdgcn_fdot2(__builtin_bit_cast(h2, a), __builtin_bit_cast(h2, b), c, false);
#else
  float r = c;
  asm("v_dot2_f32_f16 %0, %1, %2, %0" : "+v"(r) : "v"(a), "v"(b));
  return r;
#endif
}

#define U4C(v,c) ((c)==0?(v).x:((c)==1?(v).y:((c)==2?(v).z:(v).w)))

// ---------------------------------------------------------------------------
// gather_a: per used (b,t) position, copy emb[tok] fp32 -> fp16 row [320]
// ---------------------------------------------------------------------------
__global__ __launch_bounds__(256) void gather_a(const int* __restrict__ ptok,
                                                const int* __restrict__ qtok,
                                                const float* __restrict__ emb,
                                                _Float16* __restrict__ Agp,
                                                _Float16* __restrict__ Agq){
  int idx = blockIdx.x * 256 + threadIdx.x;   // chunk id
  if (idx >= (25600 + 3200) * 40) return;
  int ck = idx % 40;
  int row = idx / 40;
  int tokv; _Float16* dst;
  if (row < 25600){ tokv = ptok[row]; dst = Agp + (size_t)row * 320; }
  else { int r = row - 25600; tokv = qtok[r]; dst = Agq + (size_t)r * 320; }
  int c = ck * 8;
  const float* src = emb + (size_t)tokv * Ee;
  f16x8 v;
  #pragma unroll
  for (int i = 0; i < 8; ++i) v[i] = (c + i < Ee) ? (_Float16)src[c + i] : (_Float16)0.f;
  *(f16x8*)(dst + c) = v;
}

// ---------------------------------------------------------------------------
// prep_wih16: Wih fp32 [g][d][768][300] -> fp16 [g][d][768][320] padded
// ---------------------------------------------------------------------------
__global__ __launch_bounds__(256) void prep_wih16(const float* __restrict__ pW,
                                                  const float* __restrict__ qW,
                                                  _Float16* __restrict__ wih16){
  int idx = blockIdx.x * 256 + threadIdx.x;   // pair id: 2*2*768*160
  if (idx >= 2 * 2 * 768 * 160) return;
  int col2 = idx % 160;
  int r = idx / 160;           // g*1536 + d*768 + h
  int g = r / 1536;
  int dh = r % 1536;
  int c = col2 * 2;
  const float* W = g ? qW : pW;
  float2 v = make_float2(0.f, 0.f);
  if (c < Ee) v = *(const float2*)(W + (size_t)dh * Ee + c);
  h2 o = { (_Float16)v.x, (_Float16)v.y };
  *(h2*)(wih16 + (size_t)r * 320 + c) = o;
}

// ---------------------------------------------------------------------------
// prep_w16 for 1024-thread quarter-split 3-tier GRU.
// Thread t = qq*256 + j (qq in [0,4)) owns pairs p = qq*32 + ql*4 + c,
// ql in [0,8), of rows (g*256 + j), g in {0,1,2}.
// Quad (g,ql) -> tier block (each block = 1024 uint4 indexed by t):
//   R (7/gd, base 0):      rb = 0..6  <-> (ql=rb/3, g=rb%3)   [ql0,ql1 all; ql2 g0]
//   L (9/gd, base 28*1024): lb 0:(2,1) 1:(2,2) 2..7:(3..4,g) 8:(5,0)
//   S (8/gd, base 64*1024): sb 0:(5,1) 1:(5,2) 2..7:(6..7,g)
// u32 slot = (B*1024 + t)*4 + c where B = global block id.
// ---------------------------------------------------------------------------
__global__ __launch_bounds__(256) void prep_w16(const float* __restrict__ pW,
                                                const float* __restrict__ qW,
                                                unsigned* __restrict__ w16){
  int idx = blockIdx.x * 256 + threadIdx.x;   // u32 slot id (393216 total)
  if (idx >= 393216) return;
  int c = idx & 3;
  int t = (idx >> 2) & 1023;
  int B = idx >> 12;            // 0..95
  int gd, g, ql;
  if (B < 28){
    gd = B / 7; int rb = B % 7;
    ql = rb / 3; g = rb % 3;
  } else if (B < 64){
    int lb0 = B - 28; gd = lb0 / 9; int lb = lb0 % 9;
    if (lb < 2){ ql = 2; g = lb + 1; }
    else if (lb < 8){ int v = lb - 2; ql = 3 + v / 3; g = v % 3; }
    else { ql = 5; g = 0; }
  } else {
    int sb0 = B - 64; gd = sb0 / 8; int sb = sb0 % 8;
    if (sb < 2){ ql = 5; g = sb + 1; }
    else { int v = sb - 2; ql = 6 + v / 3; g = v % 3; }
  }
  int j = t & 255, qq = t >> 8;
  int p = qq * 32 + ql * 4 + c;
  int row = g * 256 + j;
  int d = gd & 1, kind = gd >> 1;
  const float* W = kind ? qW : pW;
  const float* src = W + ((size_t)d * H3 + row) * Hh + 2 * p;
  _Float16 a = (_Float16)src[0], bb = (_Float16)src[1];
  unsigned short ua, ub;
  __builtin_memcpy(&ua, &a, 2); __builtin_memcpy(&ub, &bb, 2);
  w16[idx] = (unsigned)ua | ((unsigned)ub << 16);
}

// ---------------------------------------------------------------------------
// xproj via MFMA, all-fp16 inputs, gathered A rows (r15, unchanged)
// ---------------------------------------------------------------------------
__global__ __launch_bounds__(512) void xproj_mfma(const _Float16* __restrict__ Ag,
                                                  const _Float16* __restrict__ wih16,
                                                  const float* __restrict__ bih,
                                                  _Float16* __restrict__ xp, int T){
  __shared__ __align__(16) _Float16 Af[128][72];
  __shared__ __align__(16) _Float16 Bf[128][72];
  int tid = threadIdx.x;
  int m0 = blockIdx.y * 128;
  int nt = blockIdx.x;                 // 0..11
  int d = nt / 6, h0 = (nt % 6) * 128;
  int wid = tid >> 6, lane = tid & 63;
  int wr = wid >> 2, wc = wid & 3;

  int r0 = tid >> 3;                    // 0..63
  int r1 = (tid + 512) >> 3;            // 64..127
  int cc = (tid & 7) * 8;
  const _Float16* eA0 = Ag + (size_t)(m0 + r0) * 320;
  const _Float16* eA1 = Ag + (size_t)(m0 + r1) * 320;
  const _Float16* wB0 = wih16 + ((size_t)d * H3 + h0 + r0) * 320;
  const _Float16* wB1 = wih16 + ((size_t)d * H3 + h0 + r1) * 320;

  f32x4 acc[4][2] = {};

  for (int k0 = 0; k0 < 320; k0 += 64){
    *(f16x8*)&Af[r0][cc] = *(const f16x8*)(eA0 + k0 + cc);
    *(f16x8*)&Af[r1][cc] = *(const f16x8*)(eA1 + k0 + cc);
    *(f16x8*)&Bf[r0][cc] = *(const f16x8*)(wB0 + k0 + cc);
    *(f16x8*)&Bf[r1][cc] = *(const f16x8*)(wB1 + k0 + cc);
    __syncthreads();
    #pragma unroll
    for (int kc = 0; kc < 2; ++kc){
      int kb = kc * 32 + (lane >> 4) * 8;
      f16x8 af[4], bf[2];
      #pragma unroll
      for (int i = 0; i < 4; ++i) af[i] = *(const f16x8*)&Af[wr * 64 + i * 16 + (lane & 15)][kb];
      #pragma unroll
      for (int jn = 0; jn < 2; ++jn) bf[jn] = *(const f16x8*)&Bf[wc * 32 + jn * 16 + (lane & 15)][kb];
      #pragma unroll
      for (int i = 0; i < 4; ++i)
        #pragma unroll
        for (int jn = 0; jn < 2; ++jn)
          acc[i][jn] = __builtin_amdgcn_mfma_f32_16x16x32_f16(af[i], bf[jn], acc[i][jn], 0, 0, 0);
    }
    __syncthreads();
  }

  #pragma unroll
  for (int jn = 0; jn < 2; ++jn){
    int h = h0 + wc * 32 + jn * 16 + (lane & 15);
    float bv = bih[d * H3 + h];
    #pragma unroll
    for (int i = 0; i < 4; ++i){
      #pragma unroll
      for (int r = 0; r < 4; ++r){
        int m = m0 + wr * 64 + i * 16 + (lane >> 4) * 4 + r;
        int bI = m / T, tI = m - bI * T;
        xp[(((size_t)d * Bb + bI) * T + tI) * H3 + h] = (_Float16)(acc[i][jn][r] + bv);
      }
    }
  }
}

// ---------------------------------------------------------------------------
// 3-tier GRU, 1024 threads (quarter-split): 4 waves/SIMD for TLP overlap of
// the S-stream with VALU (r7 shape, r12 tiering, pressure fit to the 64-reg
// grant measured at 1024 thr). R=28 reg / L=36 LDS / S=32 streamed u32 per
// thread. Readlanes shared 3-ways by ql. Gates on waves 0-3 (qq==0).
// ---------------------------------------------------------------------------
__global__ __launch_bounds__(1024)
void gru_kernel(const int* __restrict__ ptok,
                const int* __restrict__ qtok,
                const _Float16* __restrict__ xpp,
                const _Float16* __restrict__ xpq,
                const unsigned* __restrict__ w16,
                const float* __restrict__ pbhh,
                const float* __restrict__ qbhh,
                float* __restrict__ Hp,
                float* __restrict__ Hq){
  int wg = blockIdx.x;
  bool isp = wg < 128;
  int lw = isp ? wg : wg - 128;
  int d = lw & 1, b = lw >> 1;
  int T = isp ? Pp : Qq;
  const int* tok = (isp ? ptok : qtok) + b * T;
  const _Float16* xrow = (isp ? xpp : xpq) + ((size_t)d * Bb + b) * T * H3;
  int gd = (isp ? 0 : 2) + d;
  const float* bhh = (isp ? pbhh : qbhh) + d * H3;
  float* Hout = (isp ? Hp : Hq) + (size_t)b * T * Dd + d * Hh;

  __shared__ __align__(16) uint4 ldsW[9 * 1024];   // 147456 B
  __shared__ float part[3][3][Hh];                 // 9216 B
  __shared__ unsigned hbuf[2][128];                // 1024 B

  int t = threadIdx.x;
  int j = t & 255, qq = t >> 8, lane = t & 63;
  const uint4* u4w = (const uint4*)w16;

  // R tier: 7 blocks -> 28 u32. rb <-> (ql=rb/3, g=rb%3)
  unsigned wrR[28];
  #pragma unroll
  for (int rb = 0; rb < 7; ++rb){
    uint4 v = u4w[((size_t)gd * 7 + rb) * 1024 + t];
    wrR[4 * rb + 0] = v.x; wrR[4 * rb + 1] = v.y; wrR[4 * rb + 2] = v.z; wrR[4 * rb + 3] = v.w;
  }
  #pragma unroll
  for (int i = 0; i < 28; ++i) asm volatile("" : "+v"(wrR[i]));

  // L tier -> LDS (9 blocks for this gd)
  #pragma unroll
  for (int lb = 0; lb < 9; ++lb)
    ldsW[lb * 1024 + t] = u4w[28 * 1024 + ((size_t)gd * 9 + lb) * 1024 + t];
  const uint4* wS = u4w + 64 * 1024 + (size_t)gd * 8 * 1024;

  float bh0 = bhh[j], bh1 = bhh[Hh + j], bh2 = bhh[2 * Hh + j];
  float h_old = 0.f;
  if (t < 128) hbuf[1][t] = 0u;     // step 0 reads buf[1]
  __syncthreads();

  int t0 = d ? (T - 1) : 0;
  float pre0 = 0.f, pre1 = 0.f, pre2 = 0.f;
  if (qq == 0){
    pre0 = (float)xrow[(size_t)t0 * H3 + j];
    pre1 = (float)xrow[(size_t)t0 * H3 + Hh + j];
    pre2 = (float)xrow[(size_t)t0 * H3 + 2 * Hh + j];
  }

  for (int s = 0; s < T; ++s){
    int tt = d ? (T - 1 - s) : s;
    unsigned vh = hbuf[(s + 1) & 1][qq * 32 + (lane & 31)];
    float a0 = 0.f, a1 = 0.f, a2 = 0.f;

    // issue S group A (ql5 g1,g2)
    uint4 sA0 = wS[0 * 1024 + t], sA1 = wS[1 * 1024 + t];

    // R phase: ql0 (rb0-2), ql1 (rb3-5), ql2-g0 (rb6)
    #pragma unroll
    for (int c = 0; c < 4; ++c){
      unsigned hv = (unsigned)__builtin_amdgcn_readlane((int)vh, c);
      a0 = dot2f(wrR[0 + c], hv, a0);
      a1 = dot2f(wrR[4 + c], hv, a1);
      a2 = dot2f(wrR[8 + c], hv, a2);
    }
    #pragma unroll
    for (int c = 0; c < 4; ++c){
      unsigned hv = (unsigned)__builtin_amdgcn_readlane((int)vh, 4 + c);
      a0 = dot2f(wrR[12 + c], hv, a0);
      a1 = dot2f(wrR[16 + c], hv, a1);
      a2 = dot2f(wrR[20 + c], hv, a2);
    }
    #pragma unroll
    for (int c = 0; c < 4; ++c){
      unsigned hv = (unsigned)__builtin_amdgcn_readlane((int)vh, 8 + c);
      a0 = dot2f(wrR[24 + c], hv, a0);
    }

    // issue S group B (ql6 all gates)
    uint4 sB0 = wS[2 * 1024 + t], sB1 = wS[3 * 1024 + t], sB2 = wS[4 * 1024 + t];

    // L: ql2 g1,g2 (lb0,lb1)
    { uint4 l1 = ldsW[0 * 1024 + t], l2 = ldsW[1 * 1024 + t];
      #pragma unroll
      for (int c = 0; c < 4; ++c){
        unsigned hv = (unsigned)__builtin_amdgcn_readlane((int)vh, 8 + c);
        a1 = dot2f(U4C(l1, c), hv, a1);
        a2 = dot2f(U4C(l2, c), hv, a2);
      } }
    // L: ql3 all (lb2,3,4)
    { uint4 l0 = ldsW[2 * 1024 + t], l1 = ldsW[3 * 1024 + t], l2 = ldsW[4 * 1024 + t];
      #pragma unroll
      for (int c = 0; c < 4; ++c){
        unsigned hv = (unsigned)__builtin_amdgcn_readlane((int)vh, 12 + c);
        a0 = dot2f(U4C(l0, c), hv, a0);
        a1 = dot2f(U4C(l1, c), hv, a1);
        a2 = dot2f(U4C(l2, c), hv, a2);
      } }

    // consume S group A: ql5 g1,g2
    #pragma unroll
    for (int c = 0; c < 4; ++c){
      unsigned hv = (unsigned)__builtin_amdgcn_readlane((int)vh, 20 + c);
      a1 = dot2f(U4C(sA0, c), hv, a1);
      a2 = dot2f(U4C(sA1, c), hv, a2);
    }

    // issue S group C (ql7 all gates)
    uint4 sC0 = wS[5 * 1024 + t], sC1 = wS[6 * 1024 + t], sC2 = wS[7 * 1024 + t];

    // L: ql4 all (lb5,6,7)
    { uint4 l0 = ldsW[5 * 1024 + t], l1 = ldsW[6 * 1024 + t], l2 = ldsW[7 * 1024 + t];
      #pragma unroll
      for (int c = 0; c < 4; ++c){
        unsigned hv = (unsigned)__builtin_amdgcn_readlane((int)vh, 16 + c);
        a0 = dot2f(U4C(l0, c), hv, a0);
        a1 = dot2f(U4C(l1, c), hv, a1);
        a2 = dot2f(U4C(l2, c), hv, a2);
      } }
    // L: ql5 g0 (lb8)
    { uint4 l0 = ldsW[8 * 1024 + t];
      #pragma unroll
      for (int c = 0; c < 4; ++c){
        unsigned hv = (unsigned)__builtin_amdgcn_readlane((int)vh, 20 + c);
        a0 = dot2f(U4C(l0, c), hv, a0);
      } }

    // consume S group B: ql6 all
    #pragma unroll
    for (int c = 0; c < 4; ++c){
      unsigned hv = (unsigned)__builtin_amdgcn_readlane((int)vh, 24 + c);
      a0 = dot2f(U4C(sB0, c), hv, a0);
      a1 = dot2f(U4C(sB1, c), hv, a1);
      a2 = dot2f(U4C(sB2, c), hv, a2);
    }
    // consume S group C: ql7 all
    #pragma unroll
    for (int c = 0; c < 4; ++c){
      unsigned hv = (unsigned)__builtin_amdgcn_readlane((int)vh, 28 + c);
      a0 = dot2f(U4C(sC0, c), hv, a0);
      a1 = dot2f(U4C(sC1, c), hv, a1);
      a2 = dot2f(U4C(sC2, c), hv, a2);
    }

    if (qq != 0){
      part[qq - 1][0][j] = a0;
      part[qq - 1][1][j] = a1;
      part[qq - 1][2][j] = a2;
    }
    __syncthreads();
    if (qq == 0){
      float xt0 = pre0, xt1 = pre1, xt2 = pre2;
      if (s + 1 < T){
        int tn = d ? (T - 2 - s) : (s + 1);
        pre0 = (float)xrow[(size_t)tn * H3 + j];
        pre1 = (float)xrow[(size_t)tn * H3 + Hh + j];
        pre2 = (float)xrow[(size_t)tn * H3 + 2 * Hh + j];
      }
      float g0 = a0 + part[0][0][j] + part[1][0][j] + part[2][0][j] + bh0;
      float g1 = a1 + part[0][1][j] + part[1][1][j] + part[2][1][j] + bh1;
      float g2 = a2 + part[0][2][j] + part[1][2][j] + part[2][2][j] + bh2;
      float r = sigm(xt0 + g0);
      float z = sigm(xt1 + g1);
      float n = tanhf(xt2 + r * g2);
      float hnew = (1.f - z) * n + z * h_old;
      float m = (tok[tt] != 0) ? 1.f : 0.f;
      float hm = m * hnew + (1.f - m) * h_old;
      h_old = hm;
      ((_Float16*)hbuf[s & 1])[j] = (_Float16)hm;
      Hout[(size_t)tt * Dd + j] = hm * m;
    }
    __syncthreads();
  }
}

// ---------------------------------------------------------------------------
// Attention + logits (unchanged)
// ---------------------------------------------------------------------------
__global__ __launch_bounds__(512) void attn_kernel(const float* __restrict__ Hp,
                                                   const float* __restrict__ Hq,
                                                   const int* __restrict__ ptok,
                                                   const int* __restrict__ qtok,
                                                   const float* __restrict__ start_w,
                                                   const float* __restrict__ sbp,
                                                   const float* __restrict__ end_w,
                                                   const float* __restrict__ ebp,
                                                   float* __restrict__ out){
  extern __shared__ __align__(16) float lds[];
  float* hqs = lds;               // 50*512
  float* s2s = hqs + Qq * Dd;     // 64
  float* qms = s2s + 64;          // 64
  float* scw = qms + 64;          // 8*64
  float* aw  = scw + 512;         // 8*64

  int b = blockIdx.y, pc = blockIdx.x;
  int tid = threadIdx.x, wid = tid >> 6, lane = tid & 63;
  float sb = sbp[0], eb = ebp[0];

  float w1r[8], w2r[8], w3r[8], e1r[8], e2r[8], e3r[8];
  #pragma unroll
  for (int i = 0; i < 8; ++i){
    int c = lane * 8 + i;
    w1r[i] = start_w[c]; w2r[i] = start_w[Dd + c]; w3r[i] = start_w[2 * Dd + c];
    e1r[i] = end_w[c];   e2r[i] = end_w[Dd + c];   e3r[i] = end_w[2 * Dd + c];
  }
  for (int idx = tid; idx < Qq * Dd; idx += 512) hqs[idx] = Hq[(size_t)b * Qq * Dd + idx];
  __syncthreads();

  for (int q = wid; q < Qq; q += 8){
    float part = 0.f;
    const float* hq = hqs + q * Dd + lane * 8;
    #pragma unroll
    for (int i = 0; i < 8; ++i) part += hq[i] * w2r[i];
    part = allred(part);
    if (lane == 0){
      s2s[q] = part;
      qms[q] = (qtok[b * Qq + q] != 0) ? 1.f : 0.f;
    }
  }
  __syncthreads();

  for (int p = pc * 100 + wid; p < pc * 100 + 100; p += 8){
    const float* hprow = Hp + ((size_t)b * Pp + p) * Dd + lane * 8;
    float4 hv0 = *(const float4*)hprow;
    float4 hv1 = *(const float4*)(hprow + 4);
    float hpc[8] = {hv0.x, hv0.y, hv0.z, hv0.w, hv1.x, hv1.y, hv1.z, hv1.w};
    float hw3[8], he3[8];
    float s1 = 0.f, ed = 0.f;
    #pragma unroll
    for (int i = 0; i < 8; ++i){
      hw3[i] = hpc[i] * w3r[i];
      he3[i] = hpc[i] * e3r[i];
      s1 += hpc[i] * w1r[i];
      ed += hpc[i] * e1r[i];
    }
    #pragma unroll
    for (int off = 1; off < 64; off <<= 1){
      s1 += __shfl_xor(s1, off);
      ed += __shfl_xor(ed, off);
    }
    for (int q = 0; q < Qq; ++q){
      const float4* hq4 = (const float4*)(hqs + q * Dd + lane * 8);
      float4 a0 = hq4[0], a1 = hq4[1];
      float dot = hw3[0] * a0.x + hw3[1] * a0.y + hw3[2] * a0.z + hw3[3] * a0.w
                + hw3[4] * a1.x + hw3[5] * a1.y + hw3[6] * a1.z + hw3[7] * a1.w;
      dot = allred(dot);
      if (lane == 0) scw[wid * 64 + q] = (s1 + s2s[q] + dot + sb) * qms[q];
    }
    float v = (lane < Qq) ? scw[wid * 64 + lane] : -1e30f;
    float M = allmax(v);
    float ev = (lane < Qq) ? expf(v - M) : 0.f;
    float S = allred(ev);
    float am = (lane < Qq) ? (ev / S) * qms[lane] : 0.f;
    float Sm = allred(am);
    float af = am / (Sm + 1e-13f);
    if (lane < Qq) aw[wid * 64 + lane] = af;
    float wv[8] = {0.f, 0.f, 0.f, 0.f, 0.f, 0.f, 0.f, 0.f};
    for (int q = 0; q < Qq; ++q){
      float aq = aw[wid * 64 + q];
      const float4* hq4 = (const float4*)(hqs + q * Dd + lane * 8);
      float4 a0 = hq4[0], a1 = hq4[1];
      wv[0] += aq * a0.x; wv[1] += aq * a0.y; wv[2] += aq * a0.z; wv[3] += aq * a0.w;
      wv[4] += aq * a1.x; wv[5] += aq * a1.y; wv[6] += aq * a1.z; wv[7] += aq * a1.w;
    }
    float acc2 = 0.f, acc3 = 0.f, acc4 = 0.f, acc5 = 0.f;
    #pragma unroll
    for (int i = 0; i < 8; ++i){
      acc2 += wv[i] * w2r[i];
      acc3 += hw3[i] * wv[i];
      acc4 += wv[i] * e2r[i];
      acc5 += he3[i] * wv[i];
    }
    #pragma unroll
    for (int off = 1; off < 64; off <<= 1){
      acc2 += __shfl_xor(acc2, off);
      acc3 += __shfl_xor(acc3, off);
      acc4 += __shfl_xor(acc4, off);
      acc5 += __shfl_xor(acc5, off);
    }
    if (lane == 0){
      bool pm = (ptok[b * Pp + p] != 0);
      out[(size_t)b * Pp + p]                   = pm ? (s1 + acc2 + acc3 + sb) : NEGC;
      out[(size_t)Bb * Pp + (size_t)b * Pp + p] = pm ? (ed + acc4 + acc5 + eb) : NEGC;
    }
  }
}

// ---------------------------------------------------------------------------
// log_softmax over p (unchanged)
// ---------------------------------------------------------------------------
__global__ __launch_bounds__(512) void lsm_kernel(const int* __restrict__ ptok,
                                                  float* __restrict__ out){
  int b = blockIdx.x >> 1, sel = blockIdx.x & 1;
  const float* lg = out + (size_t)sel * Bb * Pp + (size_t)b * Pp;
  float* o = out + (size_t)(2 + sel) * Bb * Pp + (size_t)b * Pp;
  int tid = threadIdx.x;
  __shared__ float red1[8];
  __shared__ float red2[8];
  float x = -1e30f;
  if (tid < Pp) x = lg[tid] + ((ptok[b * Pp + tid] != 0) ? 0.f : LOGTINY);
  float m = allmax(x);
  if ((tid & 63) == 0) red1[tid >> 6] = m;
  __syncthreads();
  float M = red1[0];
  #pragma unroll
  for (int i = 1; i < 8; ++i) M = fmaxf(M, red1[i]);
  float e = (tid < Pp) ? expf(x - M) : 0.f;
  float s = allred(e);
  if ((tid & 63) == 0) red2[tid >> 6] = s;
  __syncthreads();
  float S = 0.f;
  #pragma unroll
  for (int i = 0; i < 8; ++i) S += red2[i];
  if (tid < Pp) o[tid] = (x - M) - logf(S);
}

// ---------------------------------------------------------------------------
extern "C" void kernel_launch(void* const* d_in, const int* in_sizes, int n_in,
                              void* d_out, int out_size, void* d_ws, size_t ws_size,
                              hipStream_t stream){
  const int*   passage  = (const int*)d_in[0];
  const int*   question = (const int*)d_in[1];
  const float* emb      = (const float*)d_in[2];
  const float* pW_ih    = (const float*)d_in[3];
  const float* pW_hh    = (const float*)d_in[4];
  const float* pb_ih    = (const float*)d_in[5];
  const float* pb_hh    = (const float*)d_in[6];
  const float* qW_ih    = (const float*)d_in[7];
  const float* qW_hh    = (const float*)d_in[8];
  const float* qb_ih    = (const float*)d_in[9];
  const float* qb_hh    = (const float*)d_in[10];
  const float* start_w  = (const float*)d_in[11];
  const float* start_b  = (const float*)d_in[12];
  const float* end_w    = (const float*)d_in[13];
  const float* end_b    = (const float*)d_in[14];
  float* out = (float*)d_out;

  // workspace layout (float-sized units)
  float*     ws    = (float*)d_ws;
  unsigned*  w16   = (unsigned*)ws;                    //   393216 u32
  _Float16*  wih16 = (_Float16*)(ws + 393216);         //   983040 halfs = 491520 f
  _Float16*  Agp   = (_Float16*)(ws + 884736);         //  8192000 halfs = 4096000 f
  _Float16*  Agq   = (_Float16*)(ws + 4980736);        //  1024000 halfs = 512000 f
  _Float16*  xpp   = (_Float16*)(ws + 5492736);        // 39321600 halfs = 19660800 f
  _Float16*  xpq   = (_Float16*)(ws + 25153536);       //  4915200 halfs = 2457600 f
  float*     Hp    = ws + 27611136;                    // 13107200 f
  float*     Hq    = ws + 40718336;                    //  1638400 f
  // total 42,356,736 floats = 169 MB

  hipLaunchKernelGGL(prep_w16, dim3(1536), dim3(256), 0, stream, pW_hh, qW_hh, w16);
  hipLaunchKernelGGL(gather_a, dim3(4500), dim3(256), 0, stream,
                     passage, question, emb, Agp, Agq);
  hipLaunchKernelGGL(prep_wih16, dim3(1920), dim3(256), 0, stream, pW_ih, qW_ih, wih16);
  hipLaunchKernelGGL(xproj_mfma, dim3(12, 200), dim3(512), 0, stream,
                     Agp, wih16, pb_ih, xpp, Pp);
  hipLaunchKernelGGL(xproj_mfma, dim3(12, 25), dim3(512), 0, stream,
                     Agq, wih16 + (size_t)2 * H3 * 320, qb_ih, xpq, Qq);
  hipLaunchKernelGGL(gru_kernel, dim3(256), dim3(1024), 0, stream,
                     passage, question, xpp, xpq, w16, pb_hh, qb_hh, Hp, Hq);
  size_t attn_lds = (size_t)(Qq * Dd + 64 + 64 + 512 + 512) * sizeof(float);
  hipLaunchKernelGGL(attn_kernel, dim3(4, 64), dim3(512), attn_lds, stream,
                     Hp, Hq, passage, question, start_w, start_b, end_w, end_b, out);
  hipLaunchKernelGGL(lsm_kernel, dim3(128), dim3(512), 0, stream, passage, out);
}